// Round 7
// baseline (163.500 us; speedup 1.0000x reference)
//
#include <hip/hip_runtime.h>
#include <hip/hip_bf16.h>
#include <stdint.h>

// MinGRU: B=8, S=4096, I=512, H=512 (fp32 in/out)
// R6: gemm -> barrier-free, LDS-free register GEMM. 1-wave blocks (64 thr),
//     each owns a 64x64 tile of BOTH z and h~. A/B fragments loaded straight
//     from global (L2) into VGPRs, double-buffered over a fully unrolled
//     K-loop; compiler emits counted vmcnt. XCD-chunked block swizzle keeps
//     each XCD's A panel resident in its 4 MiB L2.

typedef __attribute__((ext_vector_type(8))) short short8;   // 8 bf16 = 4 VGPR
typedef __attribute__((ext_vector_type(4))) float f32x4;

__device__ inline ushort f2bf(float f) {
  union { __hip_bfloat16 h; ushort u; } v;
  v.h = __float2bfloat16(f);
  return v.u;
}

// ---------------- K0: fp32 -> bf16 (x, W_z, W_h in one launch) ----------------
__global__ void cvt_all(const float* __restrict__ x,
                        const float* __restrict__ wz,
                        const float* __restrict__ wh,
                        ushort* __restrict__ xb,
                        ushort* __restrict__ wzb,
                        ushort* __restrict__ whb) {
  int i = blockIdx.x * 256 + threadIdx.x;
  for (; i < 4325376; i += 2048 * 256) {
    const float* s; ushort* d; int j;
    if (i < 4194304)      { s = x;  d = xb;  j = i; }
    else if (i < 4259840) { s = wz; d = wzb; j = i - 4194304; }
    else                  { s = wh; d = whb; j = i - 4259840; }
    float4 v = reinterpret_cast<const float4*>(s)[j];
    ushort4 o = make_ushort4(f2bf(v.x), f2bf(v.y), f2bf(v.z), f2bf(v.w));
    reinterpret_cast<ushort4*>(d)[j] = o;
  }
}

// ---------------- K1: register GEMM + gate + fused chunk summaries ----------
// grid 4096 x 64 thr. tile = XCD-chunked remap; bx in [0,512) m-tile (64 rows),
// by in [0,8) n-tile (64 h-cols of both matrices).
__global__ __launch_bounds__(64) void gemm_gate(
    const ushort* __restrict__ xb,   // [32768,512] bf16
    const ushort* __restrict__ wzb,  // [512,512] bf16
    const ushort* __restrict__ whb,  // [512,512] bf16
    const float* __restrict__ b_z,
    const float* __restrict__ b_h,
    uint* __restrict__ ab,           // [32768,512] packed (a,b) bf16
    float2* __restrict__ ABc)        // [8,512,128] chunk summaries (b,h,c)
{
  const int l  = threadIdx.x;
  const int lm = l & 15;
  const int lk = l >> 4;

  const int bid  = blockIdx.x;                    // 4096 (nwg % 8 == 0)
  const int tile = (bid & 7) * 512 + (bid >> 3);  // bijective XCD chunking
  const int bx = tile >> 3;                       // 0..511
  const int by = tile & 7;                        // 0..7
  const int m0 = bx * 64;
  const int n0 = by * 64;

  const int lane_off = lm * 512 + lk * 8;         // ushort units

  const ushort* ap[4];
  const ushort* bp[8];                            // [mat*4 + n]
  #pragma unroll
  for (int m = 0; m < 4; ++m)
    ap[m] = xb + (size_t)(m0 + m * 16) * 512 + lane_off;
  #pragma unroll
  for (int n = 0; n < 4; ++n) {
    bp[n]     = wzb + (size_t)(n0 + n * 16) * 512 + lane_off;
    bp[4 + n] = whb + (size_t)(n0 + n * 16) * 512 + lane_off;
  }

  f32x4 acc[2][4][4];
  #pragma unroll
  for (int q = 0; q < 2; ++q)
    #pragma unroll
    for (int m = 0; m < 4; ++m)
      #pragma unroll
      for (int n = 0; n < 4; ++n)
        acc[q][m][n] = (f32x4){0.f, 0.f, 0.f, 0.f};

  short8 aA[4], bA[8], aB[4], bB[8];

#define LOADT(av_, bv_, ktv)                                         \
  _Pragma("unroll") for (int m = 0; m < 4; ++m)                      \
    av_[m] = *(const short8*)(ap[m] + (ktv) * 32);                   \
  _Pragma("unroll") for (int q = 0; q < 8; ++q)                      \
    bv_[q] = *(const short8*)(bp[q] + (ktv) * 32);

#define COMPUTE(av_, bv_)                                            \
  _Pragma("unroll") for (int m = 0; m < 4; ++m)                      \
    _Pragma("unroll") for (int n = 0; n < 4; ++n) {                  \
      acc[0][m][n] = __builtin_amdgcn_mfma_f32_16x16x32_bf16(        \
          av_[m], bv_[n], acc[0][m][n], 0, 0, 0);                    \
      acc[1][m][n] = __builtin_amdgcn_mfma_f32_16x16x32_bf16(        \
          av_[m], bv_[4 + n], acc[1][m][n], 0, 0, 0);                \
    }

  LOADT(aA, bA, 0);
  #pragma unroll
  for (int kt = 0; kt < 16; kt += 2) {
    LOADT(aB, bB, kt + 1);            // prefetch odd tile
    COMPUTE(aA, bA);                  // compute even tile
    if (kt + 2 < 16) { LOADT(aA, bA, kt + 2); }
    COMPUTE(aB, bB);
  }
#undef LOADT
#undef COMPUTE

  // ---- bias ----
  float bzv[4], bhv[4];
  #pragma unroll
  for (int n = 0; n < 4; ++n) {
    int col = n0 + n * 16 + lm;
    bzv[n] = b_z[col];
    bhv[n] = b_h[col];
  }

  // ---- gate epilogue: a = 1-z, b = z*h~ ; packed bf16 pairs ----
  // C layout: row = lk*4 + j (within 16), col = lm (m89-verified).
  float av[4][4][4], bv[4][4][4];   // [m][j][n]
  #pragma unroll
  for (int m = 0; m < 4; ++m) {
    #pragma unroll
    for (int j = 0; j < 4; ++j) {
      size_t grow = (size_t)(m0 + m * 16 + lk * 4 + j);
      uint* po = ab + grow * 512 + n0 + lm;
      #pragma unroll
      for (int n = 0; n < 4; ++n) {
        float uz = acc[0][m][n][j] + bzv[n];
        float uh = acc[1][m][n][j] + bhv[n];
        float z  = 1.f / (1.f + __expf(-uz));
        float a  = 1.f - z;
        float bb = z * uh;
        av[m][j][n] = a;
        bv[m][j][n] = bb;
        po[n * 16] = (uint)f2bf(a) | ((uint)f2bf(bb) << 16);
      }
    }
  }

  // ---- fused chunk summaries: 64 rows = 2 chunks of 32 (time asc:
  // mm asc, lk asc, j asc). ABc layout: [b][h][c].
  #pragma unroll
  for (int cb = 0; cb < 2; ++cb) {
    #pragma unroll
    for (int n = 0; n < 4; ++n) {
      float At[2], Bt[2];
      #pragma unroll
      for (int mm = 0; mm < 2; ++mm) {
        float A = 1.f, Bv = 0.f;
        #pragma unroll
        for (int j = 0; j < 4; ++j) {
          float a = av[2 * cb + mm][j][n];
          float b = bv[2 * cb + mm][j][n];
          A  = a * A;
          Bv = a * Bv + b;
        }
        float Ag = 1.f, Bg = 0.f;
        #pragma unroll
        for (int q = 0; q < 4; ++q) {     // lk-segments in time order
          float Aq = __shfl(A,  lm + 16 * q);
          float Bq = __shfl(Bv, lm + 16 * q);
          Ag = Aq * Ag;
          Bg = Aq * Bg + Bq;
        }
        At[mm] = Ag;
        Bt[mm] = Bg;
      }
      float Achunk = At[1] * At[0];
      float Bchunk = At[1] * Bt[0] + Bt[1];
      if (lk == 0) {
        int bidx = bx >> 6;                       // batch (64 bx per batch)
        int c    = (bx & 63) * 2 + cb;            // chunk within batch
        int col  = n0 + n * 16 + lm;
        ABc[((size_t)bidx * 512 + col) * 128 + c] = make_float2(Achunk, Bchunk);
      }
    }
  }
}

// ---------------- K3: wave-parallel scan over chunk summaries ----------------
__global__ __launch_bounds__(256) void chunk_scan(
    const float2* __restrict__ ABc,   // [8,512,128]
    const float* __restrict__ h0,
    float* __restrict__ Hinit)        // [8,128,512]
{
  __shared__ float sm[128][4];
  const int w = threadIdx.x >> 6, l = threadIdx.x & 63;
  const int b   = blockIdx.x >> 7;
  const int h0g = (blockIdx.x & 127) * 4;
  const int h   = h0g + w;

  const float2* base = ABc + ((size_t)b * 512 + h) * 128;
  float2 s1 = base[l];
  float2 s2 = base[64 + l];

  float A1 = s1.x, B1 = s1.y;
  #pragma unroll
  for (int d = 1; d < 64; d <<= 1) {
    float uA = __shfl_up(A1, d);
    float uB = __shfl_up(B1, d);
    if (l >= d) { B1 = A1 * uB + B1; A1 = A1 * uA; }
  }
  float A2 = s2.x, B2 = s2.y;
  #pragma unroll
  for (int d = 1; d < 64; d <<= 1) {
    float uA = __shfl_up(A2, d);
    float uB = __shfl_up(B2, d);
    if (l >= d) { B2 = A2 * uB + B2; A2 = A2 * uA; }
  }
  float PA = __shfl(A1, 63), PB = __shfl(B1, 63);   // prefix of chunks 0..63
  float FA = A2 * PA;
  float FB = A2 * PB + B2;

  float e1A = __shfl_up(A1, 1), e1B = __shfl_up(B1, 1);
  if (l == 0) { e1A = 1.f; e1B = 0.f; }
  float e2A = __shfl_up(FA, 1), e2B = __shfl_up(FB, 1);
  if (l == 0) { e2A = PA; e2B = PB; }

  float h0v = h0[b * 512 + h];
  sm[l][w]      = e1A * h0v + e1B;
  sm[64 + l][w] = e2A * h0v + e2B;
  __syncthreads();

  const int tt = threadIdx.x;
  if (tt < 128) {
    float4 v = *(const float4*)sm[tt];
    *(float4*)(Hinit + ((size_t)b * 128 + tt) * 512 + h0g) = v;
  }
}

// ---------------- K4: replay each chunk from Hinit, write out ----------------
__global__ __launch_bounds__(256) void scan_write(
    const uint* __restrict__ ab,
    const float* __restrict__ Hinit,
    float* __restrict__ out)
{
  int tid = blockIdx.x * 256 + threadIdx.x;   // 131072
  int cg = tid & 127;            // h-group: h = cg*4 ..
  int c  = (tid >> 7) & 127;
  int b  = tid >> 14;
  const uint4* p = reinterpret_cast<const uint4*>(ab + ((size_t)(b * 4096 + c * 32)) * 512) + cg;
  float4 hv = *reinterpret_cast<const float4*>(Hinit + ((size_t)b * 128 + c) * 512 + cg * 4);
  float4* po = reinterpret_cast<float4*>(out + ((size_t)(b * 4096 + c * 32)) * 512) + cg;
  #pragma unroll 4
  for (int t = 0; t < 32; ++t) {
    uint4 u = p[(size_t)t * 128];
    hv.x = __uint_as_float(u.x << 16) * hv.x + __uint_as_float(u.x & 0xffff0000u);
    hv.y = __uint_as_float(u.y << 16) * hv.y + __uint_as_float(u.y & 0xffff0000u);
    hv.z = __uint_as_float(u.z << 16) * hv.z + __uint_as_float(u.z & 0xffff0000u);
    hv.w = __uint_as_float(u.w << 16) * hv.w + __uint_as_float(u.w & 0xffff0000u);
    po[(size_t)t * 128] = hv;
  }
}

extern "C" void kernel_launch(void* const* d_in, const int* in_sizes, int n_in,
                              void* d_out, int out_size, void* d_ws, size_t ws_size,
                              hipStream_t stream) {
  const float* x   = (const float*)d_in[0];
  const float* h0  = (const float*)d_in[1];
  const float* W_z = (const float*)d_in[2];
  const float* b_z = (const float*)d_in[3];
  const float* W_h = (const float*)d_in[4];
  const float* b_h = (const float*)d_in[5];
  float* out = (float*)d_out;

  char* ws = (char*)d_ws;
  ushort* xb    = (ushort*)(ws);                  // 33,554,432 B
  ushort* wzb   = (ushort*)(ws + 33554432);       //    524,288 B
  ushort* whb   = (ushort*)(ws + 34078720);       //    524,288 B
  uint*   ab    = (uint*)  (ws + 34603008);       // 67,108,864 B
  float2* ABc   = (float2*)(ws + 101711872);      //  4,194,304 B  [8,512,128]
  float*  Hinit = (float*) (ws + 105906176);      //  2,097,152 B  [8,128,512]

  cvt_all<<<2048, 256, 0, stream>>>(x, W_z, W_h, xb, wzb, whb);
  gemm_gate<<<4096, 64, 0, stream>>>(xb, wzb, whb, b_z, b_h, ab, ABc);
  chunk_scan<<<1024, 256, 0, stream>>>(ABc, h0, Hinit);
  scan_write<<<512, 256, 0, stream>>>(ab, Hinit, out);
}

// Round 8
// 98.150 us; speedup vs baseline: 1.6658x; 1.6658x over previous
//
#include <hip/hip_runtime.h>
#include <hip/hip_bf16.h>
#include <stdint.h>

// MinGRU: B=8, S=4096, I=512, H=512 (fp32 in/out)
// R7: R5's counted-vmcnt pipeline deepened to prefetch depth 3:
//     4 LDS buffers x 16 KiB (A 8K | Bz 4K | Bh 4K), BK=32, 16 K-steps.
//     Iter kt: stage(kt+3) -> s_waitcnt vmcnt(12) (tile kt landed ~3 steps
//     ago) -> s_barrier -> ds_read+MFMA (setprio) -> s_barrier.
//     Other kernels unchanged (at memory floor).

typedef __attribute__((ext_vector_type(8))) short short8;   // 8 bf16 = 4 VGPR
typedef __attribute__((ext_vector_type(4))) float f32x4;

#define AS1 __attribute__((address_space(1)))
#define AS3 __attribute__((address_space(3)))

__device__ inline void gload_lds16(const void* g, void* l) {
  __builtin_amdgcn_global_load_lds((AS1 uint32_t*)(g), (AS3 uint32_t*)(l), 16, 0, 0);
}

__device__ inline ushort f2bf(float f) {
  union { __hip_bfloat16 h; ushort u; } v;
  v.h = __float2bfloat16(f);
  return v.u;
}

// ---------------- K0: fp32 -> bf16 (x, W_z, W_h in one launch) ----------------
__global__ void cvt_all(const float* __restrict__ x,
                        const float* __restrict__ wz,
                        const float* __restrict__ wh,
                        ushort* __restrict__ xb,
                        ushort* __restrict__ wzb,
                        ushort* __restrict__ whb) {
  int i = blockIdx.x * 256 + threadIdx.x;
  for (; i < 4325376; i += 2048 * 256) {
    const float* s; ushort* d; int j;
    if (i < 4194304)      { s = x;  d = xb;  j = i; }
    else if (i < 4259840) { s = wz; d = wzb; j = i - 4194304; }
    else                  { s = wh; d = whb; j = i - 4259840; }
    float4 v = reinterpret_cast<const float4*>(s)[j];
    ushort4 o = make_ushort4(f2bf(v.x), f2bf(v.y), f2bf(v.z), f2bf(v.w));
    reinterpret_cast<ushort4*>(d)[j] = o;
  }
}

// ---------------- K1: GEMM + gate + fused chunk summaries ----------------
// grid (256, 8): m0 = bx*128, n0 = by*64. 4 waves 2x2; wave = 64 rows x 32
// h-cols of BOTH z and h~. LDS: 4 x (A 8K | Bz 4K | Bh 4K) = 64 KiB.
// BK=32, 16 K-steps, depth-3 counted-vmcnt pipeline, raw s_barrier.
// Swizzle: 4 slots of 16B per 64B row; slot ^= (row>>1)&3.
__global__ __launch_bounds__(256) void gemm_gate(
    const ushort* __restrict__ xb,   // [32768,512] bf16
    const ushort* __restrict__ wzb,  // [512,512] bf16
    const ushort* __restrict__ whb,  // [512,512] bf16
    const float* __restrict__ b_z,
    const float* __restrict__ b_h,
    uint* __restrict__ ab,           // [32768,512] packed (a,b) bf16
    float2* __restrict__ ABc)        // [8,512,128] chunk summaries (b,h,c)
{
  __shared__ __align__(16) char smem[65536];
  // buffer sel (16 KiB each): A [0,8192) = 128x32 bf16, Bz [8192,12288),
  // Bh [12288,16384)

  const int t  = threadIdx.x;
  const int w  = t >> 6;
  const int l  = t & 63;
  const int lm = l & 15;
  const int lk = l >> 4;
  const int wm = w >> 1, wn = w & 1;       // wave: rows wm*64.., cols wn*32..
  const int bx = blockIdx.x;
  const int m0 = bx * 128;
  const int n0 = blockIdx.y * 64;

  const int srow = t >> 2;     // 0..63 rows per issue
  const int ssl  = t & 3;      // 16B slot within 64B row

  f32x4 accz[4][2], acch[4][2];
  #pragma unroll
  for (int m = 0; m < 4; ++m)
    #pragma unroll
    for (int n = 0; n < 2; ++n) {
      accz[m][n] = (f32x4){0.f, 0.f, 0.f, 0.f};
      acch[m][n] = (f32x4){0.f, 0.f, 0.f, 0.f};
    }

  // Exactly 4 gload_lds per stage; no other vmcnt ops in the loop.
  auto stage = [&](int sel, int kt) {
    char* base = smem + sel * 16384;
    const int k0 = kt * 32;
    #pragma unroll
    for (int j = 0; j < 2; ++j) {          // A: 2 x 4KiB issues (64 rows each)
      int row = j * 64 + srow;
      int gs  = ssl ^ ((row >> 1) & 3);
      gload_lds16(xb + (size_t)(m0 + row) * 512 + k0 + gs * 8,
                  base + j * 4096 + w * 1024);
    }
    {
      int row = srow;
      int gs  = ssl ^ ((row >> 1) & 3);
      gload_lds16(wzb + (size_t)(n0 + row) * 512 + k0 + gs * 8,
                  base + 8192 + w * 1024);
      gload_lds16(whb + (size_t)(n0 + row) * 512 + k0 + gs * 8,
                  base + 12288 + w * 1024);
    }
  };

  stage(0, 0);
  stage(1, 1);
  stage(2, 2);                              // 12 outstanding

  #pragma unroll
  for (int kt = 0; kt < 16; ++kt) {
    const int sel = kt & 3;
    if (kt < 13) {
      stage((kt + 3) & 3, kt + 3);          // 16 outstanding
      asm volatile("s_waitcnt vmcnt(12)" ::: "memory");  // tile kt landed
    } else if (kt == 13) {
      asm volatile("s_waitcnt vmcnt(8)" ::: "memory");
    } else if (kt == 14) {
      asm volatile("s_waitcnt vmcnt(4)" ::: "memory");
    } else {
      asm volatile("s_waitcnt vmcnt(0)" ::: "memory");
    }
    __builtin_amdgcn_s_barrier();           // all waves' tile-kt data landed

    const char* base = smem + sel * 16384;
    short8 af[4], bfz[2], bfh[2];
    #pragma unroll
    for (int m = 0; m < 4; ++m) {
      int row = wm * 64 + m * 16 + lm;
      af[m] = *(const short8*)(base + row * 64 + ((lk ^ ((row >> 1) & 3)) << 4));
    }
    #pragma unroll
    for (int n = 0; n < 2; ++n) {
      int row = wn * 32 + n * 16 + lm;
      int so  = ((lk ^ ((row >> 1) & 3)) << 4);
      bfz[n] = *(const short8*)(base + 8192  + row * 64 + so);
      bfh[n] = *(const short8*)(base + 12288 + row * 64 + so);
    }
    __builtin_amdgcn_s_setprio(1);
    #pragma unroll
    for (int m = 0; m < 4; ++m)
      #pragma unroll
      for (int n = 0; n < 2; ++n) {
        accz[m][n] = __builtin_amdgcn_mfma_f32_16x16x32_bf16(af[m], bfz[n], accz[m][n], 0, 0, 0);
        acch[m][n] = __builtin_amdgcn_mfma_f32_16x16x32_bf16(af[m], bfh[n], acch[m][n], 0, 0, 0);
      }
    __builtin_amdgcn_s_setprio(0);
    __builtin_amdgcn_s_barrier();           // protect buf[(kt+3)&3] reuse
  }

  // ---- bias loads (deferred so K-loop vmcnt stays exact) ----
  float bzv[2], bhv[2];
  #pragma unroll
  for (int n = 0; n < 2; ++n) {
    int col = n0 + wn * 32 + n * 16 + lm;
    bzv[n] = b_z[col];
    bhv[n] = b_h[col];
  }

  // ---- gate epilogue: a = 1-z, b = z*h~ ; packed bf16 pairs ----
  // C layout: row = lk*4 + j (within 16), col = lm (m89-verified).
  float av[4][4][2], bv[4][4][2];
  #pragma unroll
  for (int m = 0; m < 4; ++m) {
    #pragma unroll
    for (int j = 0; j < 4; ++j) {
      size_t grow = (size_t)(m0 + wm * 64 + m * 16 + lk * 4 + j);
      uint* po = ab + grow * 512 + n0 + wn * 32 + lm;
      #pragma unroll
      for (int n = 0; n < 2; ++n) {
        float uz = accz[m][n][j] + bzv[n];
        float uh = acch[m][n][j] + bhv[n];
        float z  = 1.f / (1.f + __expf(-uz));
        float a  = 1.f - z;
        float bb = z * uh;
        av[m][j][n] = a;
        bv[m][j][n] = bb;
        po[n * 16] = (uint)f2bf(a) | ((uint)f2bf(bb) << 16);
      }
    }
  }

  // ---- fused chunk summaries: wave rows = 2 chunks of 32 (time asc:
  // mm asc, lk asc, j asc). ABc layout: [b][h][c].
  #pragma unroll
  for (int cb = 0; cb < 2; ++cb) {
    #pragma unroll
    for (int n = 0; n < 2; ++n) {
      float At[2], Bt[2];
      #pragma unroll
      for (int mm = 0; mm < 2; ++mm) {
        float A = 1.f, Bv = 0.f;
        #pragma unroll
        for (int j = 0; j < 4; ++j) {
          float a = av[2 * cb + mm][j][n];
          float b = bv[2 * cb + mm][j][n];
          A  = a * A;
          Bv = a * Bv + b;
        }
        float Ag = 1.f, Bg = 0.f;
        #pragma unroll
        for (int q = 0; q < 4; ++q) {     // lk-segments in time order
          float Aq = __shfl(A,  lm + 16 * q);
          float Bq = __shfl(Bv, lm + 16 * q);
          Ag = Aq * Ag;
          Bg = Aq * Bg + Bq;
        }
        At[mm] = Ag;
        Bt[mm] = Bg;
      }
      float Achunk = At[1] * At[0];
      float Bchunk = At[1] * Bt[0] + Bt[1];
      if (lk == 0) {
        int bidx = bx >> 5;                       // batch
        int c    = (bx & 31) * 4 + wm * 2 + cb;   // chunk within batch
        int col  = n0 + wn * 32 + n * 16 + lm;
        ABc[((size_t)bidx * 512 + col) * 128 + c] = make_float2(Achunk, Bchunk);
      }
    }
  }
}

// ---------------- K3: wave-parallel scan over chunk summaries ----------------
__global__ __launch_bounds__(256) void chunk_scan(
    const float2* __restrict__ ABc,   // [8,512,128]
    const float* __restrict__ h0,
    float* __restrict__ Hinit)        // [8,128,512]
{
  __shared__ float sm[128][4];
  const int w = threadIdx.x >> 6, l = threadIdx.x & 63;
  const int b   = blockIdx.x >> 7;
  const int h0g = (blockIdx.x & 127) * 4;
  const int h   = h0g + w;

  const float2* base = ABc + ((size_t)b * 512 + h) * 128;
  float2 s1 = base[l];
  float2 s2 = base[64 + l];

  float A1 = s1.x, B1 = s1.y;
  #pragma unroll
  for (int d = 1; d < 64; d <<= 1) {
    float uA = __shfl_up(A1, d);
    float uB = __shfl_up(B1, d);
    if (l >= d) { B1 = A1 * uB + B1; A1 = A1 * uA; }
  }
  float A2 = s2.x, B2 = s2.y;
  #pragma unroll
  for (int d = 1; d < 64; d <<= 1) {
    float uA = __shfl_up(A2, d);
    float uB = __shfl_up(B2, d);
    if (l >= d) { B2 = A2 * uB + B2; A2 = A2 * uA; }
  }
  float PA = __shfl(A1, 63), PB = __shfl(B1, 63);   // prefix of chunks 0..63
  float FA = A2 * PA;
  float FB = A2 * PB + B2;

  float e1A = __shfl_up(A1, 1), e1B = __shfl_up(B1, 1);
  if (l == 0) { e1A = 1.f; e1B = 0.f; }
  float e2A = __shfl_up(FA, 1), e2B = __shfl_up(FB, 1);
  if (l == 0) { e2A = PA; e2B = PB; }

  float h0v = h0[b * 512 + h];
  sm[l][w]      = e1A * h0v + e1B;
  sm[64 + l][w] = e2A * h0v + e2B;
  __syncthreads();

  const int tt = threadIdx.x;
  if (tt < 128) {
    float4 v = *(const float4*)sm[tt];
    *(float4*)(Hinit + ((size_t)b * 128 + tt) * 512 + h0g) = v;
  }
}

// ---------------- K4: replay each chunk from Hinit, write out ----------------
__global__ __launch_bounds__(256) void scan_write(
    const uint* __restrict__ ab,
    const float* __restrict__ Hinit,
    float* __restrict__ out)
{
  int tid = blockIdx.x * 256 + threadIdx.x;   // 131072
  int cg = tid & 127;            // h-group: h = cg*4 ..
  int c  = (tid >> 7) & 127;
  int b  = tid >> 14;
  const uint4* p = reinterpret_cast<const uint4*>(ab + ((size_t)(b * 4096 + c * 32)) * 512) + cg;
  float4 hv = *reinterpret_cast<const float4*>(Hinit + ((size_t)b * 128 + c) * 512 + cg * 4);
  float4* po = reinterpret_cast<float4*>(out + ((size_t)(b * 4096 + c * 32)) * 512) + cg;
  #pragma unroll 4
  for (int t = 0; t < 32; ++t) {
    uint4 u = p[(size_t)t * 128];
    hv.x = __uint_as_float(u.x << 16) * hv.x + __uint_as_float(u.x & 0xffff0000u);
    hv.y = __uint_as_float(u.y << 16) * hv.y + __uint_as_float(u.y & 0xffff0000u);
    hv.z = __uint_as_float(u.z << 16) * hv.z + __uint_as_float(u.z & 0xffff0000u);
    hv.w = __uint_as_float(u.w << 16) * hv.w + __uint_as_float(u.w & 0xffff0000u);
    po[(size_t)t * 128] = hv;
  }
}

extern "C" void kernel_launch(void* const* d_in, const int* in_sizes, int n_in,
                              void* d_out, int out_size, void* d_ws, size_t ws_size,
                              hipStream_t stream) {
  const float* x   = (const float*)d_in[0];
  const float* h0  = (const float*)d_in[1];
  const float* W_z = (const float*)d_in[2];
  const float* b_z = (const float*)d_in[3];
  const float* W_h = (const float*)d_in[4];
  const float* b_h = (const float*)d_in[5];
  float* out = (float*)d_out;

  char* ws = (char*)d_ws;
  ushort* xb    = (ushort*)(ws);                  // 33,554,432 B
  ushort* wzb   = (ushort*)(ws + 33554432);       //    524,288 B
  ushort* whb   = (ushort*)(ws + 34078720);       //    524,288 B
  uint*   ab    = (uint*)  (ws + 34603008);       // 67,108,864 B
  float2* ABc   = (float2*)(ws + 101711872);      //  4,194,304 B  [8,512,128]
  float*  Hinit = (float*) (ws + 105906176);      //  2,097,152 B  [8,128,512]

  cvt_all<<<2048, 256, 0, stream>>>(x, W_z, W_h, xb, wzb, whb);
  gemm_gate<<<dim3(256, 8), 256, 0, stream>>>(xb, wzb, whb, b_z, b_h, ab, ABc);
  chunk_scan<<<1024, 256, 0, stream>>>(ABc, h0, Hinit);
  scan_write<<<512, 256, 0, stream>>>(ab, Hinit, out);
}

// Round 9
// 94.546 us; speedup vs baseline: 1.7293x; 1.0381x over previous
//
#include <hip/hip_runtime.h>
#include <hip/hip_bf16.h>
#include <stdint.h>

// MinGRU: B=8, S=4096, I=512, H=512 (fp32 in/out)
// R8: gemm LDS-traffic fix — block 128x128 (both mats), wave 64x64, so each
//     ds_read_b128 feeds 2.67 MFMA (was 2): LDS bytes/FLOP halved vs R5/R7.
//     3 x 24 KiB LDS buffers, depth-2 counted-vmcnt pipeline, XCD-chunked
//     1D grid (each XCD's x panel ~4 MB = its L2). Others unchanged.

typedef __attribute__((ext_vector_type(8))) short short8;   // 8 bf16 = 4 VGPR
typedef __attribute__((ext_vector_type(4))) float f32x4;

#define AS1 __attribute__((address_space(1)))
#define AS3 __attribute__((address_space(3)))

__device__ inline void gload_lds16(const void* g, void* l) {
  __builtin_amdgcn_global_load_lds((AS1 uint32_t*)(g), (AS3 uint32_t*)(l), 16, 0, 0);
}

__device__ inline ushort f2bf(float f) {
  union { __hip_bfloat16 h; ushort u; } v;
  v.h = __float2bfloat16(f);
  return v.u;
}

// ---------------- K0: fp32 -> bf16 (x, W_z, W_h in one launch) ----------------
__global__ void cvt_all(const float* __restrict__ x,
                        const float* __restrict__ wz,
                        const float* __restrict__ wh,
                        ushort* __restrict__ xb,
                        ushort* __restrict__ wzb,
                        ushort* __restrict__ whb) {
  int i = blockIdx.x * 256 + threadIdx.x;
  for (; i < 4325376; i += 2048 * 256) {
    const float* s; ushort* d; int j;
    if (i < 4194304)      { s = x;  d = xb;  j = i; }
    else if (i < 4259840) { s = wz; d = wzb; j = i - 4194304; }
    else                  { s = wh; d = whb; j = i - 4259840; }
    float4 v = reinterpret_cast<const float4*>(s)[j];
    ushort4 o = make_ushort4(f2bf(v.x), f2bf(v.y), f2bf(v.z), f2bf(v.w));
    reinterpret_cast<ushort4*>(d)[j] = o;
  }
}

// ---------------- K1: GEMM + gate + fused chunk summaries ----------------
// grid 1024 (XCD-chunked): tile = (bid&7)*128 + bid>>3; bx = tile>>2 (m-tile,
// 128 rows), by = tile&3 (n-tile, 128 h-cols of both mats).
// 4 waves 2x2: wave = 64 rows x 64 cols x {z, h~}.
// LDS: 3 buffers x (A 8K | Bz 8K | Bh 8K) = 72 KiB. BK=32, 16 K-steps,
// depth-2 counted-vmcnt pipeline (6 issues/stage), raw s_barrier.
// Rows are 64 B; 16B-slot swizzle slot ^= (row>>1)&3 (measured conflict-free).
__global__ __launch_bounds__(256, 2) void gemm_gate(
    const ushort* __restrict__ xb,   // [32768,512] bf16
    const ushort* __restrict__ wzb,  // [512,512] bf16
    const ushort* __restrict__ whb,  // [512,512] bf16
    const float* __restrict__ b_z,
    const float* __restrict__ b_h,
    uint* __restrict__ ab,           // [32768,512] packed (a,b) bf16
    float2* __restrict__ ABc)        // [8,512,128] chunk summaries (b,h,c)
{
  __shared__ __align__(16) char smem[73728];
  // buffer (24 KiB): A [0,8192) 128x32bf16, Bz [8192,16384), Bh [16384,24576)

  const int t  = threadIdx.x;
  const int w  = t >> 6;
  const int l  = t & 63;
  const int lm = l & 15;
  const int lk = l >> 4;
  const int wm = w >> 1, wn = w & 1;       // wave: rows wm*64.., cols wn*64..
  const int bid  = blockIdx.x;
  const int tile = (bid & 7) * 128 + (bid >> 3);   // bijective (1024 % 8 == 0)
  const int bx = tile >> 2;                // 0..255
  const int by = tile & 3;                 // 0..3
  const int m0 = bx * 128;
  const int n0 = by * 128;

  const int srow = t >> 2;     // 0..63 rows per issue
  const int ssl  = t & 3;      // 16B slot within 64B row

  f32x4 acc[2][4][4];
  #pragma unroll
  for (int q = 0; q < 2; ++q)
    #pragma unroll
    for (int m = 0; m < 4; ++m)
      #pragma unroll
      for (int n = 0; n < 4; ++n)
        acc[q][m][n] = (f32x4){0.f, 0.f, 0.f, 0.f};

  // Exactly 6 gload_lds per stage; no other vmcnt ops in the loop.
  auto stage = [&](int sel, int kt) {
    char* base = smem + sel * 24576;
    const int k0 = kt * 32;
    #pragma unroll
    for (int j = 0; j < 2; ++j) {
      int row = j * 64 + srow;
      int gs  = ssl ^ ((row >> 1) & 3);
      gload_lds16(xb + (size_t)(m0 + row) * 512 + k0 + gs * 8,
                  base + j * 4096 + w * 1024);
      gload_lds16(wzb + (size_t)(n0 + row) * 512 + k0 + gs * 8,
                  base + 8192 + j * 4096 + w * 1024);
      gload_lds16(whb + (size_t)(n0 + row) * 512 + k0 + gs * 8,
                  base + 16384 + j * 4096 + w * 1024);
    }
  };

  stage(0, 0);
  stage(1, 1);                              // 12 outstanding

  #pragma unroll
  for (int kt = 0; kt < 16; ++kt) {
    const int sel = kt % 3;
    if (kt < 14) {
      stage((kt + 2) % 3, kt + 2);          // 18 outstanding
      asm volatile("s_waitcnt vmcnt(12)" ::: "memory");  // tile kt landed
    } else if (kt == 14) {
      asm volatile("s_waitcnt vmcnt(6)" ::: "memory");
    } else {
      asm volatile("s_waitcnt vmcnt(0)" ::: "memory");
    }
    __builtin_amdgcn_s_barrier();           // all waves' tile-kt data landed

    const char* base = smem + sel * 24576;
    short8 af[4], bfz[4], bfh[4];
    #pragma unroll
    for (int m = 0; m < 4; ++m) {
      int row = wm * 64 + m * 16 + lm;
      af[m] = *(const short8*)(base + row * 64 + ((lk ^ ((row >> 1) & 3)) << 4));
    }
    #pragma unroll
    for (int n = 0; n < 4; ++n) {
      int row = wn * 64 + n * 16 + lm;
      int so  = ((lk ^ ((row >> 1) & 3)) << 4);
      bfz[n] = *(const short8*)(base + 8192  + row * 64 + so);
      bfh[n] = *(const short8*)(base + 16384 + row * 64 + so);
    }
    __builtin_amdgcn_s_setprio(1);
    #pragma unroll
    for (int m = 0; m < 4; ++m)
      #pragma unroll
      for (int n = 0; n < 4; ++n) {
        acc[0][m][n] = __builtin_amdgcn_mfma_f32_16x16x32_bf16(af[m], bfz[n], acc[0][m][n], 0, 0, 0);
        acc[1][m][n] = __builtin_amdgcn_mfma_f32_16x16x32_bf16(af[m], bfh[n], acc[1][m][n], 0, 0, 0);
      }
    __builtin_amdgcn_s_setprio(0);
    __builtin_amdgcn_s_barrier();           // protect next staged buffer
  }

  // ---- gate epilogue + fused chunk summaries, per n-block to bound regs ----
  // C layout: row = lk*4 + j (within 16), col = lm (m89-verified).
  #pragma unroll
  for (int n = 0; n < 4; ++n) {
    const int col = n0 + wn * 64 + n * 16 + lm;
    const float bzn = b_z[col];
    const float bhn = b_h[col];
    float av[4][4], bv[4][4];   // [m][j]
    #pragma unroll
    for (int m = 0; m < 4; ++m) {
      #pragma unroll
      for (int j = 0; j < 4; ++j) {
        size_t grow = (size_t)(m0 + wm * 64 + m * 16 + lk * 4 + j);
        float uz = acc[0][m][n][j] + bzn;
        float uh = acc[1][m][n][j] + bhn;
        float z  = 1.f / (1.f + __expf(-uz));
        float a  = 1.f - z;
        float bb = z * uh;
        av[m][j] = a;
        bv[m][j] = bb;
        ab[grow * 512 + n0 + wn * 64 + n * 16 + lm] =
            (uint)f2bf(a) | ((uint)f2bf(bb) << 16);
      }
    }
    // chunk summaries: wave rows = 2 chunks of 32 (time asc: mm, lk, j).
    #pragma unroll
    for (int cb = 0; cb < 2; ++cb) {
      float At[2], Bt[2];
      #pragma unroll
      for (int mm = 0; mm < 2; ++mm) {
        float A = 1.f, Bv = 0.f;
        #pragma unroll
        for (int j = 0; j < 4; ++j) {
          float a = av[2 * cb + mm][j];
          float b = bv[2 * cb + mm][j];
          A  = a * A;
          Bv = a * Bv + b;
        }
        float Ag = 1.f, Bg = 0.f;
        #pragma unroll
        for (int q = 0; q < 4; ++q) {     // lk-segments in time order
          float Aq = __shfl(A,  lm + 16 * q);
          float Bq = __shfl(Bv, lm + 16 * q);
          Ag = Aq * Ag;
          Bg = Aq * Bg + Bq;
        }
        At[mm] = Ag;
        Bt[mm] = Bg;
      }
      float Achunk = At[1] * At[0];
      float Bchunk = At[1] * Bt[0] + Bt[1];
      if (lk == 0) {
        int bidx = bx >> 5;                       // batch
        int c    = (bx & 31) * 4 + wm * 2 + cb;   // chunk within batch
        ABc[((size_t)bidx * 512 + col) * 128 + c] = make_float2(Achunk, Bchunk);
      }
    }
  }
}

// ---------------- K3: wave-parallel scan over chunk summaries ----------------
__global__ __launch_bounds__(256) void chunk_scan(
    const float2* __restrict__ ABc,   // [8,512,128]
    const float* __restrict__ h0,
    float* __restrict__ Hinit)        // [8,128,512]
{
  __shared__ float sm[128][4];
  const int w = threadIdx.x >> 6, l = threadIdx.x & 63;
  const int b   = blockIdx.x >> 7;
  const int h0g = (blockIdx.x & 127) * 4;
  const int h   = h0g + w;

  const float2* base = ABc + ((size_t)b * 512 + h) * 128;
  float2 s1 = base[l];
  float2 s2 = base[64 + l];

  float A1 = s1.x, B1 = s1.y;
  #pragma unroll
  for (int d = 1; d < 64; d <<= 1) {
    float uA = __shfl_up(A1, d);
    float uB = __shfl_up(B1, d);
    if (l >= d) { B1 = A1 * uB + B1; A1 = A1 * uA; }
  }
  float A2 = s2.x, B2 = s2.y;
  #pragma unroll
  for (int d = 1; d < 64; d <<= 1) {
    float uA = __shfl_up(A2, d);
    float uB = __shfl_up(B2, d);
    if (l >= d) { B2 = A2 * uB + B2; A2 = A2 * uA; }
  }
  float PA = __shfl(A1, 63), PB = __shfl(B1, 63);   // prefix of chunks 0..63
  float FA = A2 * PA;
  float FB = A2 * PB + B2;

  float e1A = __shfl_up(A1, 1), e1B = __shfl_up(B1, 1);
  if (l == 0) { e1A = 1.f; e1B = 0.f; }
  float e2A = __shfl_up(FA, 1), e2B = __shfl_up(FB, 1);
  if (l == 0) { e2A = PA; e2B = PB; }

  float h0v = h0[b * 512 + h];
  sm[l][w]      = e1A * h0v + e1B;
  sm[64 + l][w] = e2A * h0v + e2B;
  __syncthreads();

  const int tt = threadIdx.x;
  if (tt < 128) {
    float4 v = *(const float4*)sm[tt];
    *(float4*)(Hinit + ((size_t)b * 128 + tt) * 512 + h0g) = v;
  }
}

// ---------------- K4: replay each chunk from Hinit, write out ----------------
__global__ __launch_bounds__(256) void scan_write(
    const uint* __restrict__ ab,
    const float* __restrict__ Hinit,
    float* __restrict__ out)
{
  int tid = blockIdx.x * 256 + threadIdx.x;   // 131072
  int cg = tid & 127;            // h-group: h = cg*4 ..
  int c  = (tid >> 7) & 127;
  int b  = tid >> 14;
  const uint4* p = reinterpret_cast<const uint4*>(ab + ((size_t)(b * 4096 + c * 32)) * 512) + cg;
  float4 hv = *reinterpret_cast<const float4*>(Hinit + ((size_t)b * 128 + c) * 512 + cg * 4);
  float4* po = reinterpret_cast<float4*>(out + ((size_t)(b * 4096 + c * 32)) * 512) + cg;
  #pragma unroll 4
  for (int t = 0; t < 32; ++t) {
    uint4 u = p[(size_t)t * 128];
    hv.x = __uint_as_float(u.x << 16) * hv.x + __uint_as_float(u.x & 0xffff0000u);
    hv.y = __uint_as_float(u.y << 16) * hv.y + __uint_as_float(u.y & 0xffff0000u);
    hv.z = __uint_as_float(u.z << 16) * hv.z + __uint_as_float(u.z & 0xffff0000u);
    hv.w = __uint_as_float(u.w << 16) * hv.w + __uint_as_float(u.w & 0xffff0000u);
    po[(size_t)t * 128] = hv;
  }
}

extern "C" void kernel_launch(void* const* d_in, const int* in_sizes, int n_in,
                              void* d_out, int out_size, void* d_ws, size_t ws_size,
                              hipStream_t stream) {
  const float* x   = (const float*)d_in[0];
  const float* h0  = (const float*)d_in[1];
  const float* W_z = (const float*)d_in[2];
  const float* b_z = (const float*)d_in[3];
  const float* W_h = (const float*)d_in[4];
  const float* b_h = (const float*)d_in[5];
  float* out = (float*)d_out;

  char* ws = (char*)d_ws;
  ushort* xb    = (ushort*)(ws);                  // 33,554,432 B
  ushort* wzb   = (ushort*)(ws + 33554432);       //    524,288 B
  ushort* whb   = (ushort*)(ws + 34078720);       //    524,288 B
  uint*   ab    = (uint*)  (ws + 34603008);       // 67,108,864 B
  float2* ABc   = (float2*)(ws + 101711872);      //  4,194,304 B  [8,512,128]
  float*  Hinit = (float*) (ws + 105906176);      //  2,097,152 B  [8,128,512]

  cvt_all<<<2048, 256, 0, stream>>>(x, W_z, W_h, xb, wzb, whb);
  gemm_gate<<<1024, 256, 0, stream>>>(xb, wzb, whb, b_z, b_h, ab, ABc);
  chunk_scan<<<1024, 256, 0, stream>>>(ABc, h0, Hinit);
  scan_write<<<512, 256, 0, stream>>>(ab, Hinit, out);
}